// Round 16
// baseline (42.127 us; speedup 1.0000x reference)
//
#include <hip/hip_runtime.h>

#define NDIM 1024
#define BATCH 16
#define SEG 62     // output px per wave segment (64 loaded, lanes 0/63 halo-only)
#define NSEG 17    // 17*62 = 1054 >= 1024

// R16: latency-amortized register-direct design.
// R1-R15 matrix (staging/sync/depth/occupancy/granule/conflicts/stores) all
// pinned at 36-43us; step-time analysis shows every variant degenerated to a
// ~1-step prefetch distance => 16 serialized memory round-trips per wave.
// Here: wave = one 62-px row segment x ALL 16 batches, 1 px/lane. Chunk of
// 8 batches = 24 loads issued back-to-back (6KB in flight), drained with
// strictly-decreasing literal vmcnt; 2nd chunk issued mid-drain. Latency
// exposed ~2x per wave instead of 16x. No LDS, no barriers.
// All loads unconditional (clamped addr; zero-select AFTER the wait — an
// early use would make the compiler insert its own early waitcnt).
// K built once per px in fp32 (9 regs at 1px/lane; absmax back to fp32 level).
__global__ __launch_bounds__(256) void smallsm_fused(
    const float* __restrict__ image,
    const float* __restrict__ x,
    const float* __restrict__ w,
    const float* __restrict__ bias,
    float* __restrict__ out)
{
    const int N = NDIM;
    const size_t NN = (size_t)N * N;
    const int tid  = threadIdx.x;
    const int wid  = tid >> 6;             // wave 0..3 -> row within block
    const int lane = tid & 63;
    const int jW   = blockIdx.x * SEG;     // first output px of segment
    const int jL   = jW - 1 + lane;        // this lane's loaded column
    const int jc   = jL < 0 ? 0 : (jL > N - 1 ? N - 1 : jL);   // clamped
    const int iT   = blockIdx.y * 4 + wid; // output row

    const bool rv0 = (iT > 0);
    const bool rv2 = (iT < N - 1);
    const int  r0  = rv0 ? iT - 1 : 0;     // clamped row addresses
    const int  r2  = rv2 ? iT + 1 : N - 1;
    const bool zl  = (jL == 0);            // output j==0: left neighbor = pad
    const bool zr  = (jL == N - 1);        // output j==N-1: right neighbor = pad
    const bool sv  = (lane >= 1) && (lane <= SEG) && (jL < N);  // store lanes

    // ---- phase 0: uniform w/bias + image loads (oldest in VMEM queue) ----
    float wr[9][3], br[9];
#pragma unroll
    for (int p = 0; p < 9; ++p) {
        br[p] = bias[p];
#pragma unroll
        for (int n = 0; n < 3; ++n) {
            wr[p][n] = 0.f;  // rows summed on the fly below; placeholder
        }
    }
    // load all 27 weights (uniform -> scalar loads, or old vector loads; either
    // way they are OLDER than chunk A so vmcnt(24) below covers them)
    float wv[27];
#pragma unroll
    for (int q = 0; q < 27; ++q) wv[q] = w[q * 3 - 2 * q + ((q * 0))];  // placeholder fixed below
    // NOTE: simple direct load; index math kept trivial:
#pragma unroll
    for (int q = 0; q < 27; ++q) wv[q] = w[q];          // w[p*9+m*3+n], p*9+m*3 flattened: first 27 = p0..p2
    float wv2[27];
#pragma unroll
    for (int q = 0; q < 27; ++q) wv2[q] = w[27 + q];    // p3..p5
    float wv3[27];
#pragma unroll
    for (int q = 0; q < 27; ++q) wv3[q] = w[54 + q];    // p6..p8

    const float* im0 = image + (size_t)r0 * N;
    const float* im1 = image + (size_t)iT * N;
    const float* im2 = image + (size_t)r2 * N;
    float i0 = im0[jc], i1 = im1[jc], i2 = im2[jc];
    __builtin_amdgcn_sched_barrier(0);

    // ---- phase 1: issue chunk A (batches 0..7 x 3 rows, unconditional) ----
    float xa[8][3];
#pragma unroll
    for (int b = 0; b < 8; ++b) {
        const float* xb = x + (size_t)b * NN;
        xa[b][0] = xb[(size_t)r0 * N + jc];
        xa[b][1] = xb[(size_t)iT * N + jc];
        xa[b][2] = xb[(size_t)r2 * N + jc];
    }
    __builtin_amdgcn_sched_barrier(0);

    // ---- phase 2: K build. vmcnt(24) = chunk A may remain outstanding;
    //      image + w/bias (older) are forced complete. ----
    asm volatile("s_waitcnt vmcnt(24)" ::: "memory");
    __builtin_amdgcn_sched_barrier(0);
    float k0, k1, k2, k3, k4, k5, k6, k7, k8;
    {
        float v0 = rv0 ? i0 : 0.f;
        float v1 = i1;
        float v2 = rv2 ? i2 : 0.f;
        float l0 = __shfl_up(v0, 1), rr0 = __shfl_down(v0, 1);
        float l1 = __shfl_up(v1, 1), rr1 = __shfl_down(v1, 1);
        float l2 = __shfl_up(v2, 1), rr2 = __shfl_down(v2, 1);
        if (zl) { l0 = 0.f; l1 = 0.f; l2 = 0.f; }
        if (zr) { rr0 = 0.f; rr1 = 0.f; rr2 = 0.f; }
        const float win[3][3] = { { l0, v0, rr0 }, { l1, v1, rr1 }, { l2, v2, rr2 } };
        float kk[9];
#pragma unroll
        for (int p = 0; p < 9; ++p) {
            float a = br[p];
#pragma unroll
            for (int m = 0; m < 3; ++m)
#pragma unroll
                for (int n = 0; n < 3; ++n) {
                    const int q = p * 9 + m * 3 + n;
                    const float wt = (q < 27) ? wv[q] : (q < 54) ? wv2[q - 27] : wv3[q - 54];
                    a += wt * win[m][n];
                }
            kk[p] = a;
        }
        k0 = kk[0]; k1 = kk[1]; k2 = kk[2];
        k3 = kk[3]; k4 = kk[4]; k5 = kk[5];
        k6 = kk[6]; k7 = kk[7]; k8 = kk[8];
    }

    // ---- phase 3: drain applies with literal decreasing vmcnt ----
#define APPLY(B_, ARR, I_, NIMM) do {                                      \
        asm volatile("s_waitcnt vmcnt(" #NIMM ")" ::: "memory");           \
        __builtin_amdgcn_sched_barrier(0);                                 \
        float v0 = rv0 ? ARR[I_][0] : 0.f;                                 \
        float v1 = ARR[I_][1];                                             \
        float v2 = rv2 ? ARR[I_][2] : 0.f;                                 \
        float l0 = __shfl_up(v0, 1), q0 = __shfl_down(v0, 1);              \
        float l1 = __shfl_up(v1, 1), q1 = __shfl_down(v1, 1);              \
        float l2 = __shfl_up(v2, 1), q2 = __shfl_down(v2, 1);              \
        if (zl) { l0 = 0.f; l1 = 0.f; l2 = 0.f; }                          \
        if (zr) { q0 = 0.f; q1 = 0.f; q2 = 0.f; }                          \
        float acc = k0 * l0 + k1 * v0 + k2 * q0;                           \
        acc += k3 * l1 + k4 * v1 + k5 * q1;                                \
        acc += k6 * l2 + k7 * v2 + k8 * q2;                                \
        if (sv) out[(size_t)(B_) * NN + (size_t)iT * N + jL] = acc;        \
        __builtin_amdgcn_sched_barrier(0);                                 \
    } while (0)

    // chunk A applies 0..3 (A-newer = 24-3(b+1); + b stores)
    APPLY(0, xa, 0, 21);
    APPLY(1, xa, 1, 19);
    APPLY(2, xa, 2, 17);
    APPLY(3, xa, 3, 15);

    // ---- issue chunk B (batches 8..15) while A drains ----
    float xbuf[8][3];
#pragma unroll
    for (int b = 0; b < 8; ++b) {
        const float* xb = x + (size_t)(b + 8) * NN;
        xbuf[b][0] = xb[(size_t)r0 * N + jc];
        xbuf[b][1] = xb[(size_t)iT * N + jc];
        xbuf[b][2] = xb[(size_t)r2 * N + jc];
    }
    __builtin_amdgcn_sched_barrier(0);

    // remaining A applies: N = (24-3(b+1)) A-newer + 24 B + b stores
    APPLY(4, xa, 4, 37);
    APPLY(5, xa, 5, 35);
    APPLY(6, xa, 6, 33);
    APPLY(7, xa, 7, 31);
    // chunk B applies: N = (24-3(b-7)) B-newer + b stores = 45-2b
    APPLY(8,  xbuf, 0, 29);
    APPLY(9,  xbuf, 1, 27);
    APPLY(10, xbuf, 2, 25);
    APPLY(11, xbuf, 3, 23);
    APPLY(12, xbuf, 4, 21);
    APPLY(13, xbuf, 5, 19);
    APPLY(14, xbuf, 6, 17);
    APPLY(15, xbuf, 7, 15);
#undef APPLY
}

extern "C" void kernel_launch(void* const* d_in, const int* in_sizes, int n_in,
                              void* d_out, int out_size, void* d_ws, size_t ws_size,
                              hipStream_t stream) {
    const float* image = (const float*)d_in[0];
    const float* x     = (const float*)d_in[1];
    const float* w     = (const float*)d_in[2];
    const float* bias  = (const float*)d_in[3];
    float* outp = (float*)d_out;

    dim3 grid(NSEG, NDIM / 4, 1);   // 17 x 256 = 4352 blocks, 4 waves each
    dim3 block(256);
    hipLaunchKernelGGL(smallsm_fused, grid, block, 0, stream,
                       image, x, w, bias, outp);
}

// Round 17
// 29.182 us; speedup vs baseline: 1.4436x; 1.4436x over previous
//
#include <hip/hip_runtime.h>
#include <stdint.h>

#define NDIM 1024
#define BATCH 16

typedef float fvec4 __attribute__((ext_vector_type(4)));

__device__ __forceinline__ float h2f(uint32_t bits16) {
    _Float16 h = __builtin_bit_cast(_Float16, (uint16_t)bits16);
    return (float)h;
}

// R17 = R13 (best base, 36.9us; R10 nt-variant 35.9) + XCD-aware block swizzle.
// Theory: the 36us plateau is a closed-loop latency limit — step time =
// load-service latency + compute. Each x row is read by 3 row-neighbor waves;
// default round-robin dispatch puts y-adjacent blocks on DIFFERENT XCDs, so
// 2/3 of x reads are served by L3/fabric (~400-600cy) instead of local L2
// (~200cy). Swizzle tile=(bid&7)*128+(bid>>3) gives each XCD one contiguous
// 8-block-row band (128 output rows, ~520KB/batch-step working set < 4MB L2)
// so row re-reads are XCD-local. Everything else identical to R13.
__global__ __launch_bounds__(256) void smallsm_fused(
    const float* __restrict__ image,
    const float* __restrict__ x,
    const float* __restrict__ w,
    const float* __restrict__ bias,
    float* __restrict__ out)
{
    __shared__ float Xlds[4][3][512];   // [wave][buf][6*72 used + pad] = 24576 B

    const int N = NDIM;
    const size_t NN = (size_t)N * N;
    const int tid  = threadIdx.x;
    const int wid  = tid >> 6;            // wave 0..3
    const int lane = tid & 63;
    const int tx   = lane & 15;           // 16 lanes in j (x4 px = 64 cols)
    const int g    = lane >> 4;           // row group 0..3 within wave

    // ---- XCD-aware bijective swizzle (nwg = 16*64 = 1024, 8 XCDs) ----
    // HW dispatches linear bid round-robin across XCDs (XCD = bid % 8).
    // tile = (bid&7)*128 + (bid>>3): XCD k owns tiles [k*128,(k+1)*128)
    // = block-rows [k*8,(k+1)*8) x all 16 column-tiles (y-major tiles).
    const int bid  = blockIdx.y * 16 + blockIdx.x;
    const int tile = (bid & 7) * 128 + (bid >> 3);
    const int bx   = tile & 15;           // column-tile 0..15
    const int by   = tile >> 4;           // row-tile 0..63

    const int jB   = bx * 64;
    const int jT   = jB + tx * 4;
    const int iW   = by * 16 + wid * 4;   // wave's first output row
    const int iT   = iW + g;

    const bool is_l = (tx == 0);
    const bool is_r = (tx == 15);

    // ---- staging source offsets: 2 global_load_lds per stage ----
    uint32_t soff0, soff1; bool sv0, sv1;
#pragma unroll
    for (int ii = 0; ii < 2; ++ii) {
        const int S    = ii * 64 + lane;
        const int row  = S / 18;
        const int slot = S - row * 18;
        const int colF = (slot < 16) ? slot * 4 : (slot == 16 ? -4 : 64);
        const int grow = iW - 1 + row;
        const int gcol = jB + colF;
        const bool v = (S < 108) && (grow >= 0) && (grow < N) &&
                       (gcol >= 0) && (gcol + 4 <= N);
        const uint32_t o = (uint32_t)(grow * N + gcol);
        if (ii == 0) { sv0 = v; soff0 = o; } else { sv1 = v; soff1 = o; }
    }

    auto stage = [&](int b, int buf) {
        const float* xb = x + (size_t)b * NN;
        float* lb = &Xlds[wid][buf][0];
        if (sv0)
            __builtin_amdgcn_global_load_lds(
                (const __attribute__((address_space(1))) void*)(xb + soff0),
                (__attribute__((address_space(3))) void*)(lb), 16, 0, 0);
        if (sv1)
            __builtin_amdgcn_global_load_lds(
                (const __attribute__((address_space(1))) void*)(xb + soff1),
                (__attribute__((address_space(3))) void*)(lb + 256), 16, 0, 0);
    };

    // ---- prologue: image loads (K-build input), then stages 0,1 ----
    const bool hpred = (is_l && jT > 0) || (is_r && jT + 4 < N);
    const int  hoff  = is_r ? (jT + 4) : (jT - 1);
    float im_m[3][4], im_h[3];
#pragma unroll
    for (int r = 0; r < 3; ++r) {
        const int row = iT - 1 + r;
        const bool rv = (row >= 0) && (row < N);
        const float* rp = image + (size_t)row * N;
        fvec4 mv = {0.f, 0.f, 0.f, 0.f};
        if (rv) mv = *reinterpret_cast<const fvec4*>(rp + jT);
        im_h[r] = (rv && hpred) ? rp[hoff] : 0.f;
        im_m[r][0] = mv.x; im_m[r][1] = mv.y; im_m[r][2] = mv.z; im_m[r][3] = mv.w;
    }
    __builtin_amdgcn_sched_barrier(0);
    stage(0, 0);
    stage(1, 1);
    __builtin_amdgcn_sched_barrier(0);

    // ---- build K (fp32), pack fp16x2 -> Kp[18] (runs under stage latency) ----
    uint32_t Kp[18];
    {
        float im[3][6];
#pragma unroll
        for (int r = 0; r < 3; ++r) {
            float left  = __shfl_up(im_m[r][3], 1);
            float right = __shfl_down(im_m[r][0], 1);
            if (is_l) left  = im_h[r];
            if (is_r) right = im_h[r];
            im[r][0] = left;       im[r][1] = im_m[r][0]; im[r][2] = im_m[r][1];
            im[r][3] = im_m[r][2]; im[r][4] = im_m[r][3]; im[r][5] = right;
        }
#pragma unroll
        for (int p = 0; p < 9; ++p) {
            const float bv = bias[p];
            float a0 = bv, a1 = bv, a2 = bv, a3 = bv;
#pragma unroll
            for (int m = 0; m < 3; ++m) {
#pragma unroll
                for (int n = 0; n < 3; ++n) {
                    const float wv = w[p * 9 + m * 3 + n];
                    a0 += wv * im[m][0 + n];
                    a1 += wv * im[m][1 + n];
                    a2 += wv * im[m][2 + n];
                    a3 += wv * im[m][3 + n];
                }
            }
            const uint16_t q0 = __builtin_bit_cast(uint16_t, (_Float16)a0);
            const uint16_t q1 = __builtin_bit_cast(uint16_t, (_Float16)a1);
            const uint16_t q2 = __builtin_bit_cast(uint16_t, (_Float16)a2);
            const uint16_t q3 = __builtin_bit_cast(uint16_t, (_Float16)a3);
            Kp[2 * p]     = (uint32_t)q0 | ((uint32_t)q1 << 16);
            Kp[2 * p + 1] = (uint32_t)q2 | ((uint32_t)q3 << 16);
        }
    }

    // ---- apply batch k from buffer buf (literal), store result ----
    auto apply = [&](int k, int buf) {
        const float* base = &Xlds[wid][buf][0];
        float a0 = 0.f, a1 = 0.f, a2 = 0.f, a3 = 0.f;
#pragma unroll
        for (int r = 0; r < 3; ++r) {
            const float* rp = base + (g + r) * 72;
            const bool rv = ((unsigned)(iT - 1 + r) < (unsigned)N);
            fvec4 m = *reinterpret_cast<const fvec4*>(rp + 4 * tx);
            float lft = is_l ? rp[67] : rp[4 * tx - 1];
            float rgt = is_r ? rp[68] : rp[4 * tx + 4];
            if (is_l && jB == 0)      lft = 0.f;
            if (is_r && jB + 64 >= N) rgt = 0.f;
            if (!rv) { m.x = 0.f; m.y = 0.f; m.z = 0.f; m.w = 0.f; lft = 0.f; rgt = 0.f; }
            const float wv[6] = { lft, m.x, m.y, m.z, m.w, rgt };
#pragma unroll
            for (int l = 0; l < 3; ++l) {
                const int p = 3 * r + l;
                const uint32_t u0 = Kp[2 * p], u1 = Kp[2 * p + 1];
                a0 += h2f(u0 & 0xffffu) * wv[l + 0];
                a1 += h2f(u0 >> 16)     * wv[l + 1];
                a2 += h2f(u1 & 0xffffu) * wv[l + 2];
                a3 += h2f(u1 >> 16)     * wv[l + 3];
            }
        }
        fvec4 res; res.x = a0; res.y = a1; res.z = a2; res.w = a3;
        fvec4* dst = reinterpret_cast<fvec4*>(
            out + (size_t)k * NN + (size_t)iT * N + jT);
        *dst = res;
    };

    // ---- barrier-free 16-batch pipeline (identical to R13) ----
#define WAITV(NIMM) do {                                              \
        asm volatile("s_waitcnt vmcnt(" #NIMM ")" ::: "memory");      \
        __builtin_amdgcn_sched_barrier(0);                            \
    } while (0)
#define STEP(K_, BUFR, BUFW, NIMM) do {                               \
        WAITV(NIMM);                                                  \
        if ((K_) + 2 < BATCH) stage((K_) + 2, BUFW);                  \
        __builtin_amdgcn_sched_barrier(0);                            \
        apply((K_), BUFR);                                            \
    } while (0)

    STEP(0,  0, 2, 2);
    STEP(1,  1, 0, 3);
    STEP(2,  2, 1, 4);
    STEP(3,  0, 2, 4);
    STEP(4,  1, 0, 4);
    STEP(5,  2, 1, 4);
    STEP(6,  0, 2, 4);
    STEP(7,  1, 0, 4);
    STEP(8,  2, 1, 4);
    STEP(9,  0, 2, 4);
    STEP(10, 1, 0, 4);
    STEP(11, 2, 1, 4);
    STEP(12, 0, 2, 4);
    STEP(13, 1, 0, 4);
    STEP(14, 2, 0, 4);   // no stage(16); BUFW unused
    STEP(15, 0, 0, 2);   // no stage(17); only st13,st14 newer than s15
#undef STEP
#undef WAITV
}

extern "C" void kernel_launch(void* const* d_in, const int* in_sizes, int n_in,
                              void* d_out, int out_size, void* d_ws, size_t ws_size,
                              hipStream_t stream) {
    const float* image = (const float*)d_in[0];
    const float* x     = (const float*)d_in[1];
    const float* w     = (const float*)d_in[2];
    const float* bias  = (const float*)d_in[3];
    float* outp = (float*)d_out;

    dim3 grid(NDIM / 64, NDIM / 16, 1);
    dim3 block(256);
    hipLaunchKernelGGL(smallsm_fused, grid, block, 0, stream,
                       image, x, w, bias, outp);
}